// Round 1
// baseline (324.555 us; speedup 1.0000x reference)
//
#include <hip/hip_runtime.h>
#include <hip/hip_bf16.h>

// Problem constants (fixed by reference setup_inputs)
#define LQ      8500
#define LEN_IN  8500
#define C_DIM   256
#define N_H     8
#define N_L     4
#define N_P     4
#define D_HEAD  32

// ---------------------------------------------------------------------------
// Generic row-blocked GEMM:  Out[M x NOUT] = A[M x 256] @ W[256 x NOUT] + bias
// Block: NOUT threads, ROWS rows of A staged in LDS. Thread j owns column j.
// ---------------------------------------------------------------------------
template<int NOUT, int ROWS>
__global__ __launch_bounds__(NOUT)
void gemm_bias(const float* __restrict__ A, const float* __restrict__ W,
               const float* __restrict__ bias, float* __restrict__ Out, int M)
{
    __shared__ __align__(16) float As[ROWS][C_DIM];
    const int r0  = blockIdx.x * ROWS;
    const int tid = threadIdx.x;

    // stage A rows into LDS
    for (int idx = tid; idx < ROWS * C_DIM; idx += NOUT) {
        int r = idx >> 8, k = idx & 255;
        int row = r0 + r;
        As[r][k] = (row < M) ? A[row * C_DIM + k] : 0.f;
    }
    __syncthreads();

    float acc[ROWS];
#pragma unroll
    for (int r = 0; r < ROWS; ++r) acc[r] = 0.f;

    for (int k = 0; k < C_DIM; k += 4) {
        const float w0 = W[(k + 0) * NOUT + tid];
        const float w1 = W[(k + 1) * NOUT + tid];
        const float w2 = W[(k + 2) * NOUT + tid];
        const float w3 = W[(k + 3) * NOUT + tid];
#pragma unroll
        for (int r = 0; r < ROWS; ++r) {
            const float4 a = *reinterpret_cast<const float4*>(&As[r][k]);
            acc[r] = fmaf(a.x, w0, acc[r]);
            acc[r] = fmaf(a.y, w1, acc[r]);
            acc[r] = fmaf(a.z, w2, acc[r]);
            acc[r] = fmaf(a.w, w3, acc[r]);
        }
    }

    const float b = bias[tid];
#pragma unroll
    for (int r = 0; r < ROWS; ++r) {
        int row = r0 + r;
        if (row < M) Out[row * NOUT + tid] = acc[r] + b;
    }
}

// ---------------------------------------------------------------------------
// Fused softmax + deformable bilinear sampling.
// One block per query, 256 threads.
//   threads 0..127: combo c = h*16 + l*4 + p -> softmax + 4 corner (idx, w)
//   all 256 threads: t -> (h = t>>5, dd = t&31), gather-accumulate 64 samples
// ---------------------------------------------------------------------------
__global__ __launch_bounds__(256)
void msda_sample(const float* __restrict__ value,   // (LEN_IN, 256)
                 const float* __restrict__ off,     // (LQ, 256)
                 const float* __restrict__ attnL,   // (LQ, 128)
                 const float* __restrict__ refp,    // (LQ, 4, 2)
                 const int*   __restrict__ shapes,  // (4, 2)  [H, W]
                 const int*   __restrict__ lstart,  // (4,)
                 float* __restrict__ out)           // (LQ, 256)
{
    __shared__ int   s_idx[128][4];
    __shared__ float s_w[128][4];

    const int q = blockIdx.x;
    const int t = threadIdx.x;

    if (t < 128) {
        const int h  = t >> 4;
        const int lp = t & 15;
        const int l  = lp >> 2;
        const int Hs = shapes[2 * l + 0];
        const int Ws = shapes[2 * l + 1];
        const int st = lstart[l];

        const float ox = off[q * 256 + (h * 16 + lp) * 2 + 0];
        const float oy = off[q * 256 + (h * 16 + lp) * 2 + 1];
        const float rx = refp[q * 8 + l * 2 + 0];
        const float ry = refp[q * 8 + l * 2 + 1];

        const float locx = rx + ox / (float)Ws;
        const float locy = ry + oy / (float)Hs;
        const float x = locx * (float)Ws - 0.5f;
        const float y = locy * (float)Hs - 0.5f;
        const float x0f = floorf(x), y0f = floorf(y);
        const float lw = x - x0f, lh = y - y0f;
        const int   x0 = (int)x0f, y0 = (int)y0f;

        // per-head softmax over the 16 (l,p) combos (lanes grouped by 16)
        const float logit = attnL[q * 128 + t];
        float m = logit;
        for (int s = 8; s >= 1; s >>= 1) m = fmaxf(m, __shfl_xor(m, s, 16));
        const float e = __expf(logit - m);
        float ssum = e;
        for (int s = 8; s >= 1; s >>= 1) ssum += __shfl_xor(ssum, s, 16);
        const float a = e / ssum;

#pragma unroll
        for (int corner = 0; corner < 4; ++corner) {
            const int dy = corner >> 1, dx = corner & 1;
            const int hc = y0 + dy, wc = x0 + dx;
            const bool valid = (hc >= 0) && (hc < Hs) && (wc >= 0) && (wc < Ws);
            const float wy = dy ? lh : (1.f - lh);
            const float wx = dx ? lw : (1.f - lw);
            const int hcc = min(max(hc, 0), Hs - 1);
            const int wcc = min(max(wc, 0), Ws - 1);
            s_idx[t][corner] = st + hcc * Ws + wcc;
            s_w[t][corner]   = valid ? (wy * wx * a) : 0.f;
        }
    }
    __syncthreads();

    const int h = t >> 5, dd = t & 31;
    float acc = 0.f;
#pragma unroll
    for (int lp = 0; lp < 16; ++lp) {
        const int c = h * 16 + lp;
#pragma unroll
        for (int corner = 0; corner < 4; ++corner) {
            const float w  = s_w[c][corner];
            const int   ix = s_idx[c][corner];
            acc = fmaf(w, value[ix * 256 + h * 32 + dd], acc);
        }
    }
    out[q * 256 + t] = acc;
}

// ---------------------------------------------------------------------------
extern "C" void kernel_launch(void* const* d_in, const int* in_sizes, int n_in,
                              void* d_out, int out_size, void* d_ws, size_t ws_size,
                              hipStream_t stream)
{
    const float* query  = (const float*)d_in[0];
    const float* refp   = (const float*)d_in[1];
    const float* inflat = (const float*)d_in[2];
    const int*   shapes = (const int*)  d_in[3];
    const int*   lstart = (const int*)  d_in[4];
    const float* W_off  = (const float*)d_in[5];
    const float* b_off  = (const float*)d_in[6];
    const float* W_attn = (const float*)d_in[7];
    const float* b_attn = (const float*)d_in[8];
    const float* W_v    = (const float*)d_in[9];
    const float* b_v    = (const float*)d_in[10];
    const float* W_out  = (const float*)d_in[11];
    const float* b_out  = (const float*)d_in[12];

    float* out = (float*)d_out;

    char* ws = (char*)d_ws;
    const size_t SZ_256 = (size_t)LQ * 256 * sizeof(float);   // 8,704,000
    const size_t SZ_128 = (size_t)LQ * 128 * sizeof(float);   // 4,352,000
    float* value = (float*)(ws);
    float* offb  = (float*)(ws + SZ_256);
    float* attnL = (float*)(ws + 2 * SZ_256);
    float* msda  = (float*)(ws + 2 * SZ_256 + SZ_128);

    const int ROWS = 32;
    const int nblk = (LQ + ROWS - 1) / ROWS;  // 266

    gemm_bias<256, 32><<<nblk, 256, 0, stream>>>(inflat, W_v,   b_v,   value, LEN_IN);
    gemm_bias<256, 32><<<nblk, 256, 0, stream>>>(query,  W_off, b_off, offb,  LQ);
    gemm_bias<128, 32><<<nblk, 128, 0, stream>>>(query,  W_attn, b_attn, attnL, LQ);
    msda_sample<<<LQ, 256, 0, stream>>>(value, offb, attnL, refp, shapes, lstart, msda);
    gemm_bias<256, 32><<<nblk, 256, 0, stream>>>(msda, W_out, b_out, out, LQ);
}

// Round 2
// 78.795 us; speedup vs baseline: 4.1190x; 4.1190x over previous
//
#include <hip/hip_runtime.h>

#define LQ      8500
#define C_DIM   256

typedef __attribute__((ext_vector_type(8))) short bf16x8;
typedef __attribute__((ext_vector_type(4))) float f32x4;

__device__ __forceinline__ unsigned short f2bf(float x) {
    union { float f; unsigned u; } c; c.f = x;
    unsigned r = c.u + 0x7FFFu + ((c.u >> 16) & 1u);
    return (unsigned short)(r >> 16);
}
__device__ __forceinline__ float bf2f(unsigned us) {
    union { unsigned u; float f; } c; c.u = us << 16;
    return c.f;
}

// ---------------------------------------------------------------------------
// prep: transpose+convert weights to bf16 [N][K] layout, concat off/attn
// weights into one 384-col matrix, concat biases.
// ---------------------------------------------------------------------------
__global__ __launch_bounds__(256)
void prep(const float* __restrict__ Wv,   const float* __restrict__ Wout,
          const float* __restrict__ Woff, const float* __restrict__ Wattn,
          const float* __restrict__ boff, const float* __restrict__ battn,
          unsigned short* __restrict__ Wv_t, unsigned short* __restrict__ Wout_t,
          unsigned short* __restrict__ Wcat_t, float* __restrict__ bcat)
{
    const int total = 65536 * 3 + 32768 + 384;
    for (int i = blockIdx.x * blockDim.x + threadIdx.x; i < total;
         i += gridDim.x * blockDim.x) {
        if (i < 65536) {
            int k = i >> 8, n = i & 255;
            Wv_t[n * 256 + k] = f2bf(Wv[i]);
        } else if (i < 131072) {
            int j = i - 65536; int k = j >> 8, n = j & 255;
            Wout_t[n * 256 + k] = f2bf(Wout[j]);
        } else if (i < 196608) {
            int j = i - 131072; int k = j >> 8, n = j & 255;
            Wcat_t[n * 256 + k] = f2bf(Woff[j]);
        } else if (i < 229376) {
            int j = i - 196608; int k = j >> 7, n = j & 127;
            Wcat_t[(256 + n) * 256 + k] = f2bf(Wattn[j]);
        } else {
            int j = i - 229376;
            bcat[j] = (j < 256) ? boff[j] : battn[j - 256];
        }
    }
}

// ---------------------------------------------------------------------------
// MFMA GEMM: Out[M x N] = A[M x 256] @ Bt^T + bias   (Bt is [N][256] bf16)
// 64x64 tile, BK=32, 256 threads = 4 waves (2x2), each wave a 32x32 sub-tile.
// A is f32 (converted during staging) or bf16 per template flag.
// ---------------------------------------------------------------------------
template<bool A_F32, bool OUT_BF16>
__global__ __launch_bounds__(256)
void gemm_mfma(const void* __restrict__ Av, const unsigned short* __restrict__ Bt,
               const float* __restrict__ bias, void* __restrict__ Outv,
               int M, int N)
{
    constexpr int K = 256;
    __shared__ __align__(16) unsigned short As[64][40];
    __shared__ __align__(16) unsigned short Bs[64][40];

    const int t    = threadIdx.x;
    const int r0   = blockIdx.x * 64, c0 = blockIdx.y * 64;
    const int lane = t & 63, wave = t >> 6;
    const int wr   = wave >> 1, wc = wave & 1;
    const int lrow = lane & 15, lgrp = lane >> 4;
    const int srow = t >> 2, schunk = (t & 3) * 8;   // staging: row, k-offset

    f32x4 acc00 = {}, acc01 = {}, acc10 = {}, acc11 = {};

    const int arow = r0 + srow;
    for (int k0 = 0; k0 < K; k0 += 32) {
        bf16x8 av;
        if (arow < M) {
            if constexpr (A_F32) {
                const float* p = (const float*)Av + (size_t)arow * K + k0 + schunk;
#pragma unroll
                for (int i = 0; i < 8; ++i) av[i] = (short)f2bf(p[i]);
            } else {
                av = *(const bf16x8*)((const unsigned short*)Av +
                                      (size_t)arow * K + k0 + schunk);
            }
        } else {
#pragma unroll
            for (int i = 0; i < 8; ++i) av[i] = 0;
        }
        bf16x8 bv = *(const bf16x8*)(Bt + (size_t)(c0 + srow) * K + k0 + schunk);
        *(bf16x8*)&As[srow][schunk] = av;
        *(bf16x8*)&Bs[srow][schunk] = bv;
        __syncthreads();

        bf16x8 a0 = *(const bf16x8*)&As[wr * 32 +      lrow][lgrp * 8];
        bf16x8 a1 = *(const bf16x8*)&As[wr * 32 + 16 + lrow][lgrp * 8];
        bf16x8 b0 = *(const bf16x8*)&Bs[wc * 32 +      lrow][lgrp * 8];
        bf16x8 b1 = *(const bf16x8*)&Bs[wc * 32 + 16 + lrow][lgrp * 8];
        acc00 = __builtin_amdgcn_mfma_f32_16x16x32_bf16(a0, b0, acc00, 0, 0, 0);
        acc01 = __builtin_amdgcn_mfma_f32_16x16x32_bf16(a0, b1, acc01, 0, 0, 0);
        acc10 = __builtin_amdgcn_mfma_f32_16x16x32_bf16(a1, b0, acc10, 0, 0, 0);
        acc11 = __builtin_amdgcn_mfma_f32_16x16x32_bf16(a1, b1, acc11, 0, 0, 0);
        __syncthreads();
    }

    const f32x4 accs[2][2] = {{acc00, acc01}, {acc10, acc11}};
#pragma unroll
    for (int mi = 0; mi < 2; ++mi)
#pragma unroll
        for (int nj = 0; nj < 2; ++nj) {
            const int col = c0 + wc * 32 + nj * 16 + lrow;
            const float bb = bias[col];
#pragma unroll
            for (int j = 0; j < 4; ++j) {
                const int row = r0 + wr * 32 + mi * 16 + lgrp * 4 + j;
                if (row < M) {
                    const float v = accs[mi][nj][j] + bb;
                    if constexpr (OUT_BF16)
                        ((unsigned short*)Outv)[(size_t)row * N + col] = f2bf(v);
                    else
                        ((float*)Outv)[(size_t)row * N + col] = v;
                }
            }
        }
}

// ---------------------------------------------------------------------------
// Fused softmax + deformable bilinear sampling. 128 threads per query.
// Phase 1: thread t = combo (h = t>>4, l = (t>>2)&3, p = t&3): softmax +
//          4 corner (idx, weight) into LDS.
// Phase 2: thread t = (h = t>>4, channel pair dp = t&15): gather 64 bf16x2
//          samples, accumulate, store bf16x2.
// ---------------------------------------------------------------------------
__global__ __launch_bounds__(128)
void msda_sample(const unsigned short* __restrict__ value,   // (LEN_IN,256) bf16
                 const float* __restrict__ offattn,          // (LQ,384) f32
                 const float* __restrict__ refp,             // (LQ,4,2)
                 const int*   __restrict__ shapes,           // (4,2)
                 const int*   __restrict__ lstart,           // (4,)
                 unsigned short* __restrict__ msda)          // (LQ,256) bf16
{
    __shared__ int   s_idx[128][4];
    __shared__ float s_w[128][4];

    const int q = blockIdx.x;
    const int t = threadIdx.x;

    {
        const int lp = t & 15, l = lp >> 2;
        const int Hs = shapes[2 * l + 0];
        const int Ws = shapes[2 * l + 1];
        const int st = lstart[l];

        const float ox = offattn[(size_t)q * 384 + 2 * t + 0];
        const float oy = offattn[(size_t)q * 384 + 2 * t + 1];
        const float rx = refp[q * 8 + l * 2 + 0];
        const float ry = refp[q * 8 + l * 2 + 1];

        const float x = (rx + ox / (float)Ws) * (float)Ws - 0.5f;
        const float y = (ry + oy / (float)Hs) * (float)Hs - 0.5f;
        const float x0f = floorf(x), y0f = floorf(y);
        const float lw = x - x0f, lh = y - y0f;
        const int   x0 = (int)x0f, y0 = (int)y0f;

        const float logit = offattn[(size_t)q * 384 + 256 + t];
        float m = logit;
        for (int s = 8; s >= 1; s >>= 1) m = fmaxf(m, __shfl_xor(m, s, 16));
        const float e = __expf(logit - m);
        float ssum = e;
        for (int s = 8; s >= 1; s >>= 1) ssum += __shfl_xor(ssum, s, 16);
        const float a = e / ssum;

#pragma unroll
        for (int corner = 0; corner < 4; ++corner) {
            const int dy = corner >> 1, dx = corner & 1;
            const int hc = y0 + dy, wc = x0 + dx;
            const bool valid = (hc >= 0) && (hc < Hs) && (wc >= 0) && (wc < Ws);
            const float wy = dy ? lh : (1.f - lh);
            const float wx = dx ? lw : (1.f - lw);
            const int hcc = min(max(hc, 0), Hs - 1);
            const int wcc = min(max(wc, 0), Ws - 1);
            s_idx[t][corner] = st + hcc * Ws + wcc;
            s_w[t][corner]   = valid ? (wy * wx * a) : 0.f;
        }
    }
    __syncthreads();

    const int h = t >> 4, dp = t & 15;
    const unsigned short* vb = value + h * 32 + dp * 2;
    float a0 = 0.f, a1 = 0.f;
#pragma unroll
    for (int lp = 0; lp < 16; ++lp) {
        const int c = h * 16 + lp;
#pragma unroll
        for (int corner = 0; corner < 4; ++corner) {
            const float w  = s_w[c][corner];
            const int   ix = s_idx[c][corner];
            const unsigned v = *(const unsigned*)(vb + (size_t)ix * 256);
            a0 = fmaf(w, bf2f(v & 0xffffu), a0);
            a1 = fmaf(w, bf2f(v >> 16), a1);
        }
    }
    const unsigned o = (unsigned)f2bf(a0) | ((unsigned)f2bf(a1) << 16);
    *(unsigned*)(msda + (size_t)q * 256 + h * 32 + dp * 2) = o;
}

// ---------------------------------------------------------------------------
extern "C" void kernel_launch(void* const* d_in, const int* in_sizes, int n_in,
                              void* d_out, int out_size, void* d_ws, size_t ws_size,
                              hipStream_t stream)
{
    const float* query  = (const float*)d_in[0];
    const float* refp   = (const float*)d_in[1];
    const float* inflat = (const float*)d_in[2];
    const int*   shapes = (const int*)  d_in[3];
    const int*   lstart = (const int*)  d_in[4];
    const float* W_off  = (const float*)d_in[5];
    const float* b_attn = (const float*)d_in[8];
    const float* W_attn = (const float*)d_in[7];
    const float* b_off  = (const float*)d_in[6];
    const float* W_v    = (const float*)d_in[9];
    const float* b_v    = (const float*)d_in[10];
    const float* W_out  = (const float*)d_in[11];
    const float* b_out  = (const float*)d_in[12];

    float* out = (float*)d_out;
    char*  ws  = (char*)d_ws;

    unsigned short* Wv_t   = (unsigned short*)(ws);                    // 131072 B
    unsigned short* Wout_t = (unsigned short*)(ws + 131072);           // 131072 B
    unsigned short* Wcat_t = (unsigned short*)(ws + 262144);           // 196608 B
    float*          bcat   = (float*)         (ws + 458752);           //   1536 B
    unsigned short* value  = (unsigned short*)(ws + 460288);           // 4352000 B
    float*          offattn= (float*)         (ws + 4812288);         // 13056000 B
    unsigned short* msda   = (unsigned short*)(ws + 17868288);         // 4352000 B

    prep<<<256, 256, 0, stream>>>(W_v, W_out, W_off, W_attn, b_off, b_attn,
                                  Wv_t, Wout_t, Wcat_t, bcat);

    gemm_mfma<true, true ><<<dim3(133, 4), 256, 0, stream>>>(
        inflat, Wv_t, b_v, value, LQ, 256);
    gemm_mfma<true, false><<<dim3(133, 6), 256, 0, stream>>>(
        query, Wcat_t, bcat, offattn, LQ, 384);

    msda_sample<<<LQ, 128, 0, stream>>>(value, offattn, refp, shapes, lstart, msda);

    gemm_mfma<false, false><<<dim3(133, 4), 256, 0, stream>>>(
        msda, Wout_t, b_out, out, LQ, 256);
}

// Round 3
// 62.036 us; speedup vs baseline: 5.2317x; 1.2701x over previous
//
#include <hip/hip_runtime.h>

#define LQ    8500
#define C_DIM 256

typedef __attribute__((ext_vector_type(8))) short bf16x8;
typedef __attribute__((ext_vector_type(4))) float f32x4;

__device__ __forceinline__ unsigned short f2bf(float x) {
    union { float f; unsigned u; } c; c.f = x;
    unsigned r = c.u + 0x7FFFu + ((c.u >> 16) & 1u);
    return (unsigned short)(r >> 16);
}
__device__ __forceinline__ float bf2f(unsigned us) {
    union { unsigned u; float f; } c; c.u = us << 16;
    return c.f;
}

__device__ __forceinline__ void gload_lds16(const void* g, void* l) {
    __builtin_amdgcn_global_load_lds(
        (const __attribute__((address_space(1))) unsigned int*)g,
        (__attribute__((address_space(3))) unsigned int*)l, 16, 0, 0);
}

// ---------------------------------------------------------------------------
// prep: bf16-convert query & inflat (vectorized); transpose+convert weights
// to [N][K] bf16; concat off/attn weights (384 cols) and biases.
// ---------------------------------------------------------------------------
__global__ __launch_bounds__(256)
void prep_all(const float* __restrict__ query, const float* __restrict__ inflat,
              const float* __restrict__ Wv,   const float* __restrict__ Wout,
              const float* __restrict__ Woff, const float* __restrict__ Wattn,
              const float* __restrict__ boff, const float* __restrict__ battn,
              unsigned short* __restrict__ qbf,  unsigned short* __restrict__ ibf,
              unsigned short* __restrict__ Wv_t, unsigned short* __restrict__ Wout_t,
              unsigned short* __restrict__ Wcat_t, float* __restrict__ bcat)
{
    const int NV = LQ * 256 / 8;              // 272000 vec8 chunks per matrix
    const int tid    = blockIdx.x * 256 + threadIdx.x;
    const int stride = gridDim.x * 256;

    for (int v = tid; v < 2 * NV; v += stride) {
        const float*    src = (v < NV) ? query + (size_t)v * 8 : inflat + (size_t)(v - NV) * 8;
        unsigned short* dst = (v < NV) ? qbf   + (size_t)v * 8 : ibf    + (size_t)(v - NV) * 8;
        const float4 f0 = ((const float4*)src)[0];
        const float4 f1 = ((const float4*)src)[1];
        bf16x8 o;
        o[0] = (short)f2bf(f0.x); o[1] = (short)f2bf(f0.y);
        o[2] = (short)f2bf(f0.z); o[3] = (short)f2bf(f0.w);
        o[4] = (short)f2bf(f1.x); o[5] = (short)f2bf(f1.y);
        o[6] = (short)f2bf(f1.z); o[7] = (short)f2bf(f1.w);
        *(bf16x8*)dst = o;
    }

    const int total = 65536 * 3 + 32768 + 384;
    for (int i = tid; i < total; i += stride) {
        if (i < 65536) {
            int k = i >> 8, n = i & 255;
            Wv_t[n * 256 + k] = f2bf(Wv[i]);
        } else if (i < 131072) {
            int j = i - 65536; int k = j >> 8, n = j & 255;
            Wout_t[n * 256 + k] = f2bf(Wout[j]);
        } else if (i < 196608) {
            int j = i - 131072; int k = j >> 8, n = j & 255;
            Wcat_t[n * 256 + k] = f2bf(Woff[j]);
        } else if (i < 229376) {
            int j = i - 196608; int k = j >> 7, n = j & 127;
            Wcat_t[(256 + n) * 256 + k] = f2bf(Wattn[j]);
        } else {
            int j = i - 229376;
            bcat[j] = (j < 256) ? boff[j] : battn[j - 256];
        }
    }
}

// ---------------------------------------------------------------------------
// MFMA GEMM body: Out[M x N] = A[M x 256] @ Bt^T + bias, Bt is [N][256] bf16.
// 64x64 tile, BK=64, 256 threads = 4 waves (2x2), global_load_lds staging
// with XOR-swizzled source (LDS dest linear), swizzled ds_read_b128,
// double-buffered, 1 barrier per K-iter.
// ---------------------------------------------------------------------------
template<bool OUT_BF16>
__device__ __forceinline__ void gemm_body(
    const unsigned short* __restrict__ A, const unsigned short* __restrict__ Bt,
    const float* __restrict__ bias, void* __restrict__ Out,
    int M, int N, int r0, int c0,
    unsigned short* As, unsigned short* Bs)   // each [2][64][64]
{
    const int t    = threadIdx.x;
    const int lane = t & 63, wave = t >> 6;
    const int wr   = wave >> 1, wc = wave & 1;
    const int lrow = lane & 15, lgrp = lane >> 4;

    f32x4 acc[2][2] = {{{}, {}}, {{}, {}}};

    auto stage = [&](int buf, int k0) {
#pragma unroll
        for (int r = 0; r < 2; ++r) {
            const int row   = r * 32 + (t >> 3);
            const int chunk = (t & 7) ^ (row & 7);
            const unsigned short* g =
                A + (size_t)min(r0 + row, M - 1) * 256 + k0 + chunk * 8;
            void* l = (char*)As + buf * 8192 + r * 4096 + wave * 1024;
            gload_lds16(g, l);
        }
#pragma unroll
        for (int r = 0; r < 2; ++r) {
            const int row   = r * 32 + (t >> 3);
            const int chunk = (t & 7) ^ (row & 7);
            const unsigned short* g = Bt + (size_t)(c0 + row) * 256 + k0 + chunk * 8;
            void* l = (char*)Bs + buf * 8192 + r * 4096 + wave * 1024;
            gload_lds16(g, l);
        }
    };

    auto compute = [&](int buf) {
#pragma unroll
        for (int kk = 0; kk < 2; ++kk) {
            bf16x8 a[2], b[2];
#pragma unroll
            for (int mi = 0; mi < 2; ++mi) {
                const int row = wr * 32 + mi * 16 + lrow;
                const int g   = kk * 4 + lgrp;
                a[mi] = *(const bf16x8*)((char*)As + buf * 8192 + row * 128 +
                                         ((g ^ (row & 7)) * 16));
            }
#pragma unroll
            for (int nj = 0; nj < 2; ++nj) {
                const int row = wc * 32 + nj * 16 + lrow;
                const int g   = kk * 4 + lgrp;
                b[nj] = *(const bf16x8*)((char*)Bs + buf * 8192 + row * 128 +
                                         ((g ^ (row & 7)) * 16));
            }
#pragma unroll
            for (int mi = 0; mi < 2; ++mi)
#pragma unroll
                for (int nj = 0; nj < 2; ++nj)
                    acc[mi][nj] = __builtin_amdgcn_mfma_f32_16x16x32_bf16(
                        a[mi], b[nj], acc[mi][nj], 0, 0, 0);
        }
    };

    stage(0, 0);
    __syncthreads();
    int cur = 0;
#pragma unroll
    for (int it = 0; it < 3; ++it) {
        stage(cur ^ 1, (it + 1) * 64);
        compute(cur);
        __syncthreads();
        cur ^= 1;
    }
    compute(cur);

#pragma unroll
    for (int mi = 0; mi < 2; ++mi)
#pragma unroll
        for (int nj = 0; nj < 2; ++nj) {
            const int col = c0 + wc * 32 + nj * 16 + lrow;
            const float bb = bias[col];
#pragma unroll
            for (int j = 0; j < 4; ++j) {
                const int row = r0 + wr * 32 + mi * 16 + lgrp * 4 + j;
                if (row < M) {
                    const float v = acc[mi][nj][j] + bb;
                    if (OUT_BF16)
                        ((unsigned short*)Out)[(size_t)row * N + col] = f2bf(v);
                    else
                        ((float*)Out)[(size_t)row * N + col] = v;
                }
            }
        }
}

// fused value-proj (y<4, bf16 out) + off/attn-proj (y>=4, f32 out)
__global__ __launch_bounds__(256)
void gemm_dual(const unsigned short* __restrict__ A0, const unsigned short* __restrict__ B0,
               const float* __restrict__ bias0, unsigned short* __restrict__ out0,
               const unsigned short* __restrict__ A1, const unsigned short* __restrict__ B1,
               const float* __restrict__ bias1, float* __restrict__ out1)
{
    __shared__ __align__(16) unsigned short As[2][64][64];
    __shared__ __align__(16) unsigned short Bs[2][64][64];
    const int y  = blockIdx.y;
    const int r0 = blockIdx.x * 64;
    if (y < 4)
        gemm_body<true>(A0, B0, bias0, out0, LQ, 256, r0, y * 64,
                        &As[0][0][0], &Bs[0][0][0]);
    else
        gemm_body<false>(A1, B1, bias1, out1, LQ, 384, r0, (y - 4) * 64,
                         &As[0][0][0], &Bs[0][0][0]);
}

__global__ __launch_bounds__(256)
void gemm_f32out(const unsigned short* __restrict__ A, const unsigned short* __restrict__ Bt,
                 const float* __restrict__ bias, float* __restrict__ out)
{
    __shared__ __align__(16) unsigned short As[2][64][64];
    __shared__ __align__(16) unsigned short Bs[2][64][64];
    gemm_body<false>(A, Bt, bias, out, LQ, 256, blockIdx.x * 64, blockIdx.y * 64,
                     &As[0][0][0], &Bs[0][0][0]);
}

// ---------------------------------------------------------------------------
// Fused softmax + deformable bilinear sampling. 128 threads per query.
// Phase 1: thread t = combo (h,l,p): softmax + 4 corner (idx, weight) in LDS.
// Phase 2: t -> (h = t>>4, lphalf = (t>>3)&1, chunk = t&7): each thread
//          gathers 32 uint2 (4 bf16 channels), partner-reduce via shfl_xor(8).
// ---------------------------------------------------------------------------
__global__ __launch_bounds__(128)
void msda_sample(const unsigned short* __restrict__ value,   // (LEN_IN,256) bf16
                 const float* __restrict__ offattn,          // (LQ,384) f32
                 const float* __restrict__ refp,             // (LQ,4,2)
                 const int*   __restrict__ shapes,           // (4,2)
                 const int*   __restrict__ lstart,           // (4,)
                 unsigned short* __restrict__ msda)          // (LQ,256) bf16
{
    __shared__ int   s_idx[128][4];
    __shared__ float s_w[128][4];

    const int q = blockIdx.x;
    const int t = threadIdx.x;

    {
        const int lp = t & 15, l = lp >> 2;
        const int Hs = shapes[2 * l + 0];
        const int Ws = shapes[2 * l + 1];
        const int st = lstart[l];

        const float2 oxy = *(const float2*)(offattn + (size_t)q * 384 + 2 * t);
        const float rx = refp[q * 8 + l * 2 + 0];
        const float ry = refp[q * 8 + l * 2 + 1];

        const float x = (rx + oxy.x / (float)Ws) * (float)Ws - 0.5f;
        const float y = (ry + oxy.y / (float)Hs) * (float)Hs - 0.5f;
        const float x0f = floorf(x), y0f = floorf(y);
        const float lw = x - x0f, lh = y - y0f;
        const int   x0 = (int)x0f, y0 = (int)y0f;

        const float logit = offattn[(size_t)q * 384 + 256 + t];
        float m = logit;
        for (int s = 8; s >= 1; s >>= 1) m = fmaxf(m, __shfl_xor(m, s, 16));
        const float e = __expf(logit - m);
        float ssum = e;
        for (int s = 8; s >= 1; s >>= 1) ssum += __shfl_xor(ssum, s, 16);
        const float a = e / ssum;

#pragma unroll
        for (int corner = 0; corner < 4; ++corner) {
            const int dy = corner >> 1, dx = corner & 1;
            const int hc = y0 + dy, wc = x0 + dx;
            const bool valid = (hc >= 0) && (hc < Hs) && (wc >= 0) && (wc < Ws);
            const float wy = dy ? lh : (1.f - lh);
            const float wx = dx ? lw : (1.f - lw);
            const int hcc = min(max(hc, 0), Hs - 1);
            const int wcc = min(max(wc, 0), Ws - 1);
            s_idx[t][corner] = st + hcc * Ws + wcc;
            s_w[t][corner]   = valid ? (wy * wx * a) : 0.f;
        }
    }
    __syncthreads();

    const int chunk = t & 7, lphalf = (t >> 3) & 1, h = t >> 4;
    const unsigned short* vb = value + h * 32 + chunk * 4;
    float a0 = 0.f, a1 = 0.f, a2 = 0.f, a3 = 0.f;
#pragma unroll
    for (int j = 0; j < 8; ++j) {
        const int c = h * 16 + lphalf * 8 + j;
#pragma unroll
        for (int corner = 0; corner < 4; ++corner) {
            const float w  = s_w[c][corner];
            const size_t ix = (size_t)s_idx[c][corner];
            const uint2 v = *(const uint2*)(vb + ix * 256);
            a0 = fmaf(w, bf2f(v.x & 0xffffu), a0);
            a1 = fmaf(w, bf2f(v.x >> 16), a1);
            a2 = fmaf(w, bf2f(v.y & 0xffffu), a2);
            a3 = fmaf(w, bf2f(v.y >> 16), a3);
        }
    }
    a0 += __shfl_xor(a0, 8);
    a1 += __shfl_xor(a1, 8);
    a2 += __shfl_xor(a2, 8);
    a3 += __shfl_xor(a3, 8);
    if (!lphalf) {
        uint2 o;
        o.x = (unsigned)f2bf(a0) | ((unsigned)f2bf(a1) << 16);
        o.y = (unsigned)f2bf(a2) | ((unsigned)f2bf(a3) << 16);
        *(uint2*)(msda + (size_t)q * 256 + h * 32 + chunk * 4) = o;
    }
}

// ---------------------------------------------------------------------------
extern "C" void kernel_launch(void* const* d_in, const int* in_sizes, int n_in,
                              void* d_out, int out_size, void* d_ws, size_t ws_size,
                              hipStream_t stream)
{
    const float* query  = (const float*)d_in[0];
    const float* refp   = (const float*)d_in[1];
    const float* inflat = (const float*)d_in[2];
    const int*   shapes = (const int*)  d_in[3];
    const int*   lstart = (const int*)  d_in[4];
    const float* W_off  = (const float*)d_in[5];
    const float* b_off  = (const float*)d_in[6];
    const float* W_attn = (const float*)d_in[7];
    const float* b_attn = (const float*)d_in[8];
    const float* W_v    = (const float*)d_in[9];
    const float* b_v    = (const float*)d_in[10];
    const float* W_out  = (const float*)d_in[11];
    const float* b_out  = (const float*)d_in[12];

    float* out = (float*)d_out;
    char*  ws  = (char*)d_ws;

    size_t o = 0;
    unsigned short* qbf    = (unsigned short*)(ws + o); o += (size_t)LQ * 256 * 2;  // 4,352,000
    unsigned short* ibf    = (unsigned short*)(ws + o); o += (size_t)LQ * 256 * 2;
    unsigned short* Wv_t   = (unsigned short*)(ws + o); o += 131072;
    unsigned short* Wout_t = (unsigned short*)(ws + o); o += 131072;
    unsigned short* Wcat_t = (unsigned short*)(ws + o); o += 196608;
    float*          bcat   = (float*)         (ws + o); o += 1536;
    unsigned short* value  = (unsigned short*)(ws + o); o += (size_t)LQ * 256 * 2;
    float*          offattn= (float*)         (ws + o); o += (size_t)LQ * 384 * 4;
    unsigned short* msda   = (unsigned short*)(ws + o);

    prep_all<<<1024, 256, 0, stream>>>(query, inflat, W_v, W_out, W_off, W_attn,
                                       b_off, b_attn, qbf, ibf,
                                       Wv_t, Wout_t, Wcat_t, bcat);

    gemm_dual<<<dim3(133, 10), 256, 0, stream>>>(ibf, Wv_t, b_v, value,
                                                 qbf, Wcat_t, bcat, offattn);

    msda_sample<<<LQ, 128, 0, stream>>>(value, offattn, refp, shapes, lstart, msda);

    gemm_f32out<<<dim3(133, 4), 256, 0, stream>>>(msda, Wout_t, b_out, out);
}